// Round 8
// baseline (2353.476 us; speedup 1.0000x reference)
//
#include <hip/hip_runtime.h>
#include <cstdint>

#define NN 50000
#define EE 800000
#define GG 64

typedef unsigned short u16;
typedef __attribute__((ext_vector_type(8))) short bf16x8;
typedef __attribute__((ext_vector_type(4))) float f32x4;

__device__ __forceinline__ float bf2f(u16 v) { return __uint_as_float(((unsigned)v) << 16); }
__device__ __forceinline__ u16 f2bf(float f) {
  unsigned u = __float_as_uint(f);
  return (u16)((u + 0x7fffu + ((u >> 16) & 1u)) >> 16);
}

__device__ __forceinline__ void gload_lds16(const void* g, void* l) {
  __builtin_amdgcn_global_load_lds(
      (const __attribute__((address_space(1))) void*)g,
      (__attribute__((address_space(3))) void*)l,
      16, 0, 0);
}

__global__ void k_sentinel(float* out) { out[threadIdx.x] = 1e12f; }

// ---------------- merged histograms: in-degree (dst) + out-degree (src) ------
__global__ __launch_bounds__(256) void k_hist(const int* __restrict__ ei,
                                              int* __restrict__ deg,
                                              int* __restrict__ outdeg) {
  int i = blockIdx.x * 256 + threadIdx.x;
  if (i < EE) {
    atomicAdd(&outdeg[ei[i]], 1);
    atomicAdd(&deg[ei[EE + i]], 1);
  }
}

// one block per graph: binary-search boundaries in sorted batch, reduce outdeg.
__global__ __launch_bounds__(256) void k_graph_feats(const int* __restrict__ batch,
                                                     const int* __restrict__ outdeg,
                                                     float* __restrict__ gf) {
  __shared__ int red[256];
  int g = blockIdx.x, tid = threadIdx.x;
  auto lb = [&](int v) {
    int lo = 0, hi = NN;
    while (lo < hi) { int m = (lo + hi) >> 1; if (batch[m] < v) lo = m + 1; else hi = m; }
    return lo;
  };
  int bs = lb(g), be = lb(g + 1);
  int s = 0;
  for (int i = bs + tid; i < be; i += 256) s += outdeg[i];
  red[tid] = s;
  __syncthreads();
  for (int off = 128; off > 0; off >>= 1) {
    if (tid < off) red[tid] += red[tid + off];
    __syncthreads();
  }
  if (tid == 0) {
    gf[g * 2] = logf((float)(be - bs) + 1.f);
    gf[g * 2 + 1] = logf((float)red[0] + 1.f);
  }
}

// ------- router v5: 32 nodes/block (fp32) + fused encoder output -------------
// hs_t/rs_t are [k][32] stride-32 rows: GEMV reads = wave-uniform b128
// broadcasts (conflict-free); the one-time column writes eat a 16-way b128
// conflict (~3k cy/block, <5%) — W1 L2 traffic drops 4x vs 8 nodes/block.
__global__ __launch_bounds__(256) void k_router(
    const float* __restrict__ x, const float* __restrict__ encW, const float* __restrict__ encb,
    const int* __restrict__ batch, const float* __restrict__ gf,
    const float* __restrict__ W1, const float* __restrict__ b1,
    const float* __restrict__ W2, const float* __restrict__ b2,
    float* __restrict__ sparse, u16* __restrict__ hb_out) {
  __shared__ __align__(16) float hs_t[258][32];  // [k][r], 33KB
  __shared__ __align__(16) float rs_t[256][32];  // 32KB
  __shared__ float xv[32][6];
  __shared__ float sf2[2][32];
  __shared__ float lg[32][8];
  int tid = threadIdx.x;
  int nb = blockIdx.x * 32;
  if (tid < 192) {
    int r = tid / 6, k = tid % 6;
    int node = nb + r;
    xv[r][k] = x[(node < NN ? node : NN - 1) * 6 + k];
  } else if (tid < 224) {
    int r = tid - 192;
    int node = nb + r;
    int g = batch[node < NN ? node : NN - 1];
    sf2[0][r] = gf[g * 2];
    sf2[1][r] = gf[g * 2 + 1];
  }
  __syncthreads();
  {  // encoder: thread owns column k=tid, 32 nodes
    float wcol[6];
#pragma unroll
    for (int k = 0; k < 6; ++k) wcol[k] = encW[k * 256 + tid];
    float bb = encb[tid];
    float hrow[32];
#pragma unroll
    for (int r = 0; r < 32; ++r) {
      float s = bb;
#pragma unroll
      for (int k = 0; k < 6; ++k) s += xv[r][k] * wcol[k];
      hrow[r] = fmaxf(s, 0.f);
    }
#pragma unroll
    for (int q = 0; q < 8; ++q) {
      float4 v = {hrow[q * 4], hrow[q * 4 + 1], hrow[q * 4 + 2], hrow[q * 4 + 3]};
      *(float4*)&hs_t[tid][q * 4] = v;  // one-time 16-way b128 conflict
    }
#pragma unroll
    for (int r = 0; r < 32; ++r) {
      int node = nb + r;
      if (node < NN) hb_out[(size_t)node * 256 + tid] = f2bf(hrow[r]);
    }
  }
  if (tid < 64) {  // rows 256,257 = size feats
    int c = tid >> 5, r = tid & 31;
    hs_t[256 + c][r] = sf2[c][r];
  }
  __syncthreads();
  {  // stage 1 GEMV: thread owns hidden unit j=tid; 32 accumulators
    float acc[32];
    float bb = b1[tid];
#pragma unroll
    for (int r = 0; r < 32; ++r) acc[r] = bb;
#pragma unroll 2
    for (int k = 0; k < 258; ++k) {
      float w = W1[k * 256 + tid];
#pragma unroll
      for (int q = 0; q < 8; ++q) {
        float4 hv = *(const float4*)&hs_t[k][q * 4];  // wave-uniform broadcast
        acc[q * 4 + 0] += hv.x * w;
        acc[q * 4 + 1] += hv.y * w;
        acc[q * 4 + 2] += hv.z * w;
        acc[q * 4 + 3] += hv.w * w;
      }
    }
#pragma unroll
    for (int q = 0; q < 8; ++q) {
      float4 v = {fmaxf(acc[q * 4], 0.f), fmaxf(acc[q * 4 + 1], 0.f),
                  fmaxf(acc[q * 4 + 2], 0.f), fmaxf(acc[q * 4 + 3], 0.f)};
      *(float4*)&rs_t[tid][q * 4] = v;
    }
  }
  __syncthreads();
  {  // stage 2: thread = (r,e) pair; rs_t reads broadcast within e-groups
    int r = tid >> 3, e = tid & 7;
    float s = b2[e];
#pragma unroll 4
    for (int k = 0; k < 256; ++k) s += rs_t[k][r] * W2[k * 8 + e];
    lg[r][e] = s;
  }
  __syncthreads();
  if (tid < 32) {
    int node = nb + tid;
    if (node < NN) {
      float v1 = lg[tid][0];
      int j1 = 0;
#pragma unroll
      for (int j = 1; j < 8; ++j) {
        float v = lg[tid][j];
        if (v > v1) { v1 = v; j1 = j; }
      }
      float v2 = -1e30f;
      int j2 = 0;
#pragma unroll
      for (int j = 0; j < 8; ++j) {
        if (j == j1) continue;
        float v = lg[tid][j];
        if (v > v2) { v2 = v; j2 = j; }
      }
      float ex = expf(v2 - v1);
      float wa = 1.f / (1.f + ex), wb = ex / (1.f + ex);
      float* sp = sparse + (size_t)node * 8;
#pragma unroll
      for (int j = 0; j < 8; ++j) sp[j] = 0.f;
      sp[j1] = wa;
      sp[j2] = wb;
    }
  }
}

// ---------------- CSR build (by dst) -----------------------------------------
__global__ __launch_bounds__(1024) void k_scan(const int* __restrict__ deg,
                                               int* __restrict__ rowptr) {
  __shared__ int tmp[1024];
  __shared__ int carry;
  if (threadIdx.x == 0) { carry = 0; rowptr[0] = 0; }
  __syncthreads();
  for (int base = 0; base < NN; base += 1024) {
    int i = base + threadIdx.x;
    int v = (i < NN) ? deg[i] : 0;
    tmp[threadIdx.x] = v;
    __syncthreads();
    for (int off = 1; off < 1024; off <<= 1) {
      int t = (threadIdx.x >= off) ? tmp[threadIdx.x - off] : 0;
      __syncthreads();
      tmp[threadIdx.x] += t;
      __syncthreads();
    }
    if (i < NN) rowptr[i + 1] = carry + tmp[threadIdx.x];
    int last = tmp[1023];
    __syncthreads();
    if (threadIdx.x == 0) carry += last;
    __syncthreads();
  }
}

__global__ __launch_bounds__(256) void k_fill(const int* __restrict__ ei,
                                              const int* __restrict__ rowptr,
                                              int* __restrict__ cursor, int* __restrict__ csrc) {
  int i = blockIdx.x * 256 + threadIdx.x;
  if (i < EE) {
    int s = ei[i], d = ei[EE + i];
    int pos = atomicAdd(&cursor[d], 1);
    csrc[rowptr[d] + pos] = s;
  }
}

// -------- SpMM, plain layout (layer-0 shared agg): wave per dst --------------
__global__ __launch_bounds__(256) void k_spmm256(
    const int* __restrict__ rowptr, const int* __restrict__ csrc,
    const u16* __restrict__ X, u16* __restrict__ Y) {
  int wave = threadIdx.x >> 6, lane = threadIdx.x & 63;
  int d = blockIdx.x * 4 + wave;
  if (d >= NN) return;
  int s0 = rowptr[d], s1 = rowptr[d + 1];
  int c4 = lane * 4;
  float a0 = 0.f, a1 = 0.f, a2 = 0.f, a3 = 0.f;
  int i = s0;
  for (; i + 4 <= s1; i += 4) {
    int sa = csrc[i], sb = csrc[i + 1], sc = csrc[i + 2], sd = csrc[i + 3];
    ushort4 va = *(const ushort4*)(X + sa * 256 + c4);
    ushort4 vb = *(const ushort4*)(X + sb * 256 + c4);
    ushort4 vc = *(const ushort4*)(X + sc * 256 + c4);
    ushort4 vd = *(const ushort4*)(X + sd * 256 + c4);
    a0 += bf2f(va.x) + bf2f(vb.x) + bf2f(vc.x) + bf2f(vd.x);
    a1 += bf2f(va.y) + bf2f(vb.y) + bf2f(vc.y) + bf2f(vd.y);
    a2 += bf2f(va.z) + bf2f(vb.z) + bf2f(vc.z) + bf2f(vd.z);
    a3 += bf2f(va.w) + bf2f(vb.w) + bf2f(vc.w) + bf2f(vd.w);
  }
  for (; i < s1; ++i) {
    int sa = csrc[i];
    ushort4 va = *(const ushort4*)(X + sa * 256 + c4);
    a0 += bf2f(va.x);
    a1 += bf2f(va.y);
    a2 += bf2f(va.z);
    a3 += bf2f(va.w);
  }
  ushort4 o;
  o.x = f2bf(a0); o.y = f2bf(a1); o.z = f2bf(a2); o.w = f2bf(a3);
  *(ushort4*)(Y + d * 256 + c4) = o;
}

// -------- SpMM, expert-interleaved: block per dst; launch rs/4 threads -------
__global__ __launch_bounds__(512) void k_spmm_intl(
    const int* __restrict__ rowptr, const int* __restrict__ csrc,
    const u16* __restrict__ X, u16* __restrict__ Y, int rs) {
  int d = blockIdx.x;
  int tid = threadIdx.x;
  if (tid * 4 >= rs) return;
  int s0 = rowptr[d], s1 = rowptr[d + 1];
  int c4 = tid * 4;
  float a0 = 0.f, a1 = 0.f, a2 = 0.f, a3 = 0.f;
  int i = s0;
  for (; i + 4 <= s1; i += 4) {
    int sa = csrc[i], sb = csrc[i + 1], sc = csrc[i + 2], sd = csrc[i + 3];
    ushort4 va = *(const ushort4*)(X + (size_t)sa * rs + c4);
    ushort4 vb = *(const ushort4*)(X + (size_t)sb * rs + c4);
    ushort4 vc = *(const ushort4*)(X + (size_t)sc * rs + c4);
    ushort4 vd = *(const ushort4*)(X + (size_t)sd * rs + c4);
    a0 += bf2f(va.x) + bf2f(vb.x) + bf2f(vc.x) + bf2f(vd.x);
    a1 += bf2f(va.y) + bf2f(vb.y) + bf2f(vc.y) + bf2f(vd.y);
    a2 += bf2f(va.z) + bf2f(vb.z) + bf2f(vc.z) + bf2f(vd.z);
    a3 += bf2f(va.w) + bf2f(vb.w) + bf2f(vc.w) + bf2f(vd.w);
  }
  for (; i < s1; ++i) {
    int sa = csrc[i];
    ushort4 va = *(const ushort4*)(X + (size_t)sa * rs + c4);
    a0 += bf2f(va.x);
    a1 += bf2f(va.y);
    a2 += bf2f(va.z);
    a3 += bf2f(va.w);
  }
  ushort4 o;
  o.x = f2bf(a0); o.y = f2bf(a1); o.z = f2bf(a2); o.w = f2bf(a3);
  *(ushort4*)(Y + (size_t)d * rs + c4) = o;
}

// ------------- weight transpose+bf16 (both stacks): W[m][k][j] -> Wt[m][j][k] -
__global__ __launch_bounds__(256) void k_transpose2(const float* __restrict__ Wr,
                                                    const float* __restrict__ Wn,
                                                    u16* __restrict__ WrT,
                                                    u16* __restrict__ WnT) {
  int idx = blockIdx.x * 256 + threadIdx.x;
  if (idx >= 24 * 65536) return;
  int m = idx >> 16, rem = idx & 65535;
  int k = rem >> 8, j = rem & 255;
  int o = (m << 16) + (j << 8) + k;
  WrT[o] = f2bf(Wr[idx]);
  WnT[o] = f2bf(Wn[idx]);
}

// ---------------- fused dual-source MFMA GEMM (expert-batched, strided) ------
__global__ __launch_bounds__(512) void k_gemm(
    const u16* __restrict__ X1b, size_t x1gs, int x1rs,
    const u16* __restrict__ X2b, size_t x2gs, int x2rs,
    const u16* __restrict__ W1tb, const u16* __restrict__ W2tb, size_t wst,
    const float* __restrict__ biasb, size_t bst,
    u16* __restrict__ Yb, size_t ygs, int yrs, int relu,
    const float* __restrict__ oWr, const float* __restrict__ oWn, int e0_base,
    float* __restrict__ Y4self, float* __restrict__ Y4nb, int do_out) {
  __shared__ __align__(16) char smem[49152];  // A dbuf 16KB | B dbuf 32KB
  int g = blockIdx.y;
  const u16* X1 = X1b + (size_t)g * x1gs;
  const u16* X2 = X2b + (size_t)g * x2gs;
  const u16* W1t = W1tb + (size_t)g * wst;
  const u16* W2t = W2tb + (size_t)g * wst;
  const float* bias = biasb + (size_t)g * bst;
  u16* Y = Yb + (size_t)g * ygs;
  int tid = threadIdx.x;
  int wave = tid >> 6, lane = tid & 63;
  int l15 = lane & 15, l4 = lane >> 4;
  int m0 = blockIdx.x * 128;
  int wr = wave >> 2, wc = wave & 3;
  const f32x4 fz = {0.f, 0.f, 0.f, 0.f};
  f32x4 acc[4][4];
#pragma unroll
  for (int a = 0; a < 4; ++a)
#pragma unroll
    for (int b = 0; b < 4; ++b) acc[a][b] = fz;

  auto stage = [&](int t) {
    const u16* xs = (t < 8) ? X1 : X2;
    int xrs = (t < 8) ? x1rs : x2rs;
    const u16* wsrc = (t < 8) ? W1t : W2t;
    int kb = (t & 7) * 32;
    int half = t & 1;
    {
      int flat = wave * 1024 + lane * 16;
      int row = flat >> 6, colb = flat & 63;
      int scol = colb ^ (((row >> 1) & 3) << 4);  // inverse-swizzle the SOURCE
      int gr = m0 + row;
      if (gr > NN - 1) gr = NN - 1;
      gload_lds16(xs + (size_t)gr * xrs + kb + (scol >> 1), smem + half * 8192 + flat);
    }
#pragma unroll
    for (int q = 0; q < 2; ++q) {
      int flat = q * 8192 + wave * 1024 + lane * 16;
      int row = flat >> 6, colb = flat & 63;
      int scol = colb ^ (((row >> 1) & 3) << 4);
      gload_lds16(wsrc + row * 256 + kb + (scol >> 1), smem + 16384 + half * 16384 + flat);
    }
  };

  stage(0);
  for (int kt = 0; kt < 16; ++kt) {
    asm volatile("s_waitcnt vmcnt(0)" ::: "memory");  // tile-kt loads landed
    __builtin_amdgcn_s_barrier();                     // visible to all waves
    __builtin_amdgcn_sched_barrier(0);                // keep stage below barrier
    if (kt < 15) stage(kt + 1);
    const char* Ab = smem + (kt & 1) * 8192;
    const char* Bb = smem + 16384 + (kt & 1) * 16384;
    bf16x8 af[4], bfv[4];
#pragma unroll
    for (int mi = 0; mi < 4; ++mi) {
      int r = wr * 64 + mi * 16 + l15;
      af[mi] = *(const bf16x8*)(Ab + r * 64 + ((l4 * 16) ^ (((r >> 1) & 3) << 4)));
    }
#pragma unroll
    for (int nj = 0; nj < 4; ++nj) {
      int c = wc * 64 + nj * 16 + l15;
      bfv[nj] = *(const bf16x8*)(Bb + c * 64 + ((l4 * 16) ^ (((c >> 1) & 3) << 4)));
    }
#pragma unroll
    for (int mi = 0; mi < 4; ++mi)
#pragma unroll
      for (int nj = 0; nj < 4; ++nj)
        acc[mi][nj] =
            __builtin_amdgcn_mfma_f32_16x16x32_bf16(af[mi], bfv[nj], acc[mi][nj], 0, 0, 0);
  }

  if (!do_out) {
    // epilogue: C/D map col=lane&15, row=(lane>>4)*4+reg  [m89-verified]
#pragma unroll
    for (int mi = 0; mi < 4; ++mi) {
      int rbase = m0 + wr * 64 + mi * 16 + l4 * 4;
#pragma unroll
      for (int nj = 0; nj < 4; ++nj) {
        int col = wc * 64 + nj * 16 + l15;
        float bv = bias[col];
#pragma unroll
        for (int r2 = 0; r2 < 4; ++r2) {
          int row = rbase + r2;
          if (row < NN) {
            float v = acc[mi][nj][r2] + bv;
            if (relu) v = fmaxf(v, 0.f);
            Y[(size_t)row * yrs + col] = f2bf(v);
          }
        }
      }
    }
  } else {
    // fused out-projection: he2 = relu(acc+bias); Y4self/nb = he2 @ {oWr,oWn}
    int eabs = e0_base + g;
    const float2* wr2p = (const float2*)(oWr + (size_t)eabs * 512);
    const float2* wn2p = (const float2*)(oWn + (size_t)eabs * 512);
    float bv[4]; float2 wa[4], wb[4];
#pragma unroll
    for (int nj = 0; nj < 4; ++nj) {
      int col = wc * 64 + nj * 16 + l15;
      bv[nj] = bias[col];
      wa[nj] = wr2p[col];
      wb[nj] = wn2p[col];
    }
    float* y4red = (float*)smem;  // post-barrier LDS reuse
#pragma unroll
    for (int mi = 0; mi < 4; ++mi) {
#pragma unroll
      for (int r2 = 0; r2 < 4; ++r2) {
        float p0 = 0.f, p1 = 0.f, p2 = 0.f, p3 = 0.f;
#pragma unroll
        for (int nj = 0; nj < 4; ++nj) {
          float v = fmaxf(acc[mi][nj][r2] + bv[nj], 0.f);
          p0 += v * wa[nj].x; p1 += v * wa[nj].y;
          p2 += v * wb[nj].x; p3 += v * wb[nj].y;
        }
#pragma unroll
        for (int off2 = 1; off2 < 16; off2 <<= 1) {
          p0 += __shfl_xor(p0, off2); p1 += __shfl_xor(p1, off2);
          p2 += __shfl_xor(p2, off2); p3 += __shfl_xor(p3, off2);
        }
        if (l15 == 0) {
          int lr = wr * 64 + mi * 16 + l4 * 4 + r2;
          float* q = y4red + (lr * 4 + wc) * 4;
          q[0] = p0; q[1] = p1; q[2] = p2; q[3] = p3;
        }
      }
    }
    __syncthreads();
    if (tid < 128) {
      int row = m0 + tid;
      if (row < NN) {
        float s0 = 0.f, s1 = 0.f, n0 = 0.f, n1 = 0.f;
#pragma unroll
        for (int w2 = 0; w2 < 4; ++w2) {
          const float* q = y4red + (tid * 4 + w2) * 4;
          s0 += q[0]; s1 += q[1]; n0 += q[2]; n1 += q[3];
        }
        Y4self[row * 16 + eabs * 2] = s0;
        Y4self[row * 16 + eabs * 2 + 1] = s1;
        Y4nb[row * 16 + eabs * 2] = n0;
        Y4nb[row * 16 + eabs * 2 + 1] = n1;
      }
    }
  }
}

// ---------------- single-pass combine over all 8 experts ---------------------
__global__ __launch_bounds__(256) void k_combine(
    const int* __restrict__ rowptr, const int* __restrict__ csrc,
    const float* __restrict__ Y4self, const float* __restrict__ Y4nb,
    const float* __restrict__ sparse, const float* __restrict__ ob,
    float* __restrict__ out) {
  int t = blockIdx.x * 256 + threadIdx.x;
  int d = t >> 3, e = t & 7;
  if (d >= NN) return;
  float s0 = Y4self[d * 16 + e * 2], s1 = Y4self[d * 16 + e * 2 + 1];
  float n0 = 0.f, n1 = 0.f;
  for (int i = rowptr[d]; i < rowptr[d + 1]; ++i) {
    int s = csrc[i];
    float2 v = *(const float2*)(Y4nb + s * 16 + e * 2);
    n0 += v.x;
    n1 += v.y;
  }
  float w = sparse[d * 8 + e];
  float t0 = w * (s0 + n0 + ob[e * 2]);
  float t1 = w * (s1 + n1 + ob[e * 2 + 1]);
  t0 += __shfl_xor(t0, 1); t1 += __shfl_xor(t1, 1);
  t0 += __shfl_xor(t0, 2); t1 += __shfl_xor(t1, 2);
  t0 += __shfl_xor(t0, 4); t1 += __shfl_xor(t1, 4);
  if (e == 0) {
    out[d * 2] = t0;
    out[d * 2 + 1] = t1;
  }
}

extern "C" void kernel_launch(void* const* d_in, const int* in_sizes, int n_in,
                              void* d_out, int out_size, void* d_ws, size_t ws_size,
                              hipStream_t stream) {
  const float* x = (const float*)d_in[0];
  const int* ei = (const int*)d_in[1];
  const int* batch = (const int*)d_in[2];
  const float* enc_W = (const float*)d_in[3];
  const float* enc_b = (const float*)d_in[4];
  const float* rW1 = (const float*)d_in[5];
  const float* rb1 = (const float*)d_in[6];
  const float* rW2 = (const float*)d_in[7];
  const float* rb2 = (const float*)d_in[8];
  const float* hid_Wr = (const float*)d_in[9];
  const float* hid_Wn = (const float*)d_in[10];
  const float* hid_b = (const float*)d_in[11];
  const float* out_Wr = (const float*)d_in[12];
  const float* out_Wn = (const float*)d_in[13];
  const float* out_b = (const float*)d_in[14];
  float* out = (float*)d_out;

  char* ws = (char*)d_ws;
  size_t off = 0;
  auto alloc = [&](size_t bytes) -> void* {
    void* p = ws + off;
    off = (off + bytes + 511) & ~(size_t)511;
    return p;
  };
  const size_t HBYTES = (size_t)NN * 256 * 2;      // 25.6 MB
  u16* hb = (u16*)alloc(HBYTES);
  u16* agg0 = (u16*)alloc(HBYTES);
  u16* WrT = (u16*)alloc((size_t)24 * 65536 * 2);  // 3.15 MB
  u16* WnT = (u16*)alloc((size_t)24 * 65536 * 2);
  // contiguous zero region: deg | cursor | outdeg
  int* deg = (int*)alloc((size_t)NN * 4);
  int* cursor = (int*)alloc((size_t)NN * 4);
  int* outdeg = (int*)alloc((size_t)NN * 4);
  size_t zero_bytes = (size_t)((char*)(outdeg + NN) - (char*)deg);
  int* rowptr = (int*)alloc((size_t)(NN + 1) * 4);
  int* csrc = (int*)alloc((size_t)EE * 4);  // 3.2 MB
  float* gf = (float*)alloc(GG * 2 * 4);
  float* sparse = (float*)alloc((size_t)NN * 8 * 4);   // 1.6 MB
  float* Y4self = (float*)alloc((size_t)NN * 16 * 4);  // 3.2 MB
  float* Y4nb = (float*)alloc((size_t)NN * 16 * 4);    // 3.2 MB

  // Expert group size: he+agg pair = 51.2 MB per expert. Prefer 8 (single pass,
  // fewest dispatches; gather WS 205 MB vs 256 MB L3), fall back 4/2/1.
  size_t rem = (ws_size > off) ? ws_size - off : 0;
  size_t per = 2 * HBYTES + 2048;
  int grp = (rem >= 8 * per) ? 8 : (rem >= 4 * per) ? 4 : (rem >= 2 * per) ? 2
            : (rem >= per) ? 1 : 0;
  if (grp == 0) {
    k_sentinel<<<1, 2, 0, stream>>>(out);
    return;
  }
  u16* heb = (u16*)alloc((size_t)grp * HBYTES);   // interleaved [node][g][256]
  u16* aggb = (u16*)alloc((size_t)grp * HBYTES);  // interleaved [node][g][256]
  const int RS = grp * 256;                       // interleaved row stride (elems)

  hipMemsetAsync(deg, 0, zero_bytes, stream);

  k_transpose2<<<(24 * 65536 + 255) / 256, 256, 0, stream>>>(hid_Wr, hid_Wn, WrT, WnT);
  k_hist<<<(EE + 255) / 256, 256, 0, stream>>>(ei, deg, outdeg);
  k_graph_feats<<<GG, 256, 0, stream>>>(batch, outdeg, gf);
  k_scan<<<1, 1024, 0, stream>>>(deg, rowptr);
  k_fill<<<(EE + 255) / 256, 256, 0, stream>>>(ei, rowptr, cursor, csrc);
  k_router<<<(NN + 31) / 32, 256, 0, stream>>>(x, enc_W, enc_b, batch, gf, rW1, rb1,
                                               rW2, rb2, sparse, hb);

  const int GX = (NN + 127) / 128;  // 391 gemm blocks per expert

  // shared layer-0 aggregation of h (identical input for every expert)
  k_spmm256<<<(NN + 3) / 4, 256, 0, stream>>>(rowptr, csrc, hb, agg0);
  for (int e0 = 0; e0 < 8; e0 += grp) {
    // layer 0 (batched over grp experts): plain-layout inputs -> interleaved Y
    k_gemm<<<dim3(GX, grp), 512, 0, stream>>>(
        hb, 0, 256, agg0, 0, 256, WrT + e0 * 65536, WnT + e0 * 65536, 65536,
        hid_b + e0 * 256, 256, heb, 256, RS, 1, nullptr, nullptr, 0, nullptr, nullptr, 0);
    // layer 1 (interleaved throughout)
    k_spmm_intl<<<NN, RS / 4, 0, stream>>>(rowptr, csrc, heb, aggb, RS);
    k_gemm<<<dim3(GX, grp), 512, 0, stream>>>(
        heb, 256, RS, aggb, 256, RS, WrT + (8 + e0) * 65536, WnT + (8 + e0) * 65536, 65536,
        hid_b + (8 + e0) * 256, 256, heb, 256, RS, 1, nullptr, nullptr, 0, nullptr, nullptr, 0);
    // layer 2 + fused out-projection (he2 never materialized)
    k_spmm_intl<<<NN, RS / 4, 0, stream>>>(rowptr, csrc, heb, aggb, RS);
    k_gemm<<<dim3(GX, grp), 512, 0, stream>>>(
        heb, 256, RS, aggb, 256, RS, WrT + (16 + e0) * 65536, WnT + (16 + e0) * 65536, 65536,
        hid_b + (16 + e0) * 256, 256, nullptr, 0, 256, 1, out_Wr, out_Wn, e0,
        Y4self, Y4nb, 1);
  }
  k_combine<<<(NN * 8 + 255) / 256, 256, 0, stream>>>(rowptr, csrc, Y4self, Y4nb, sparse,
                                                      out_b, out);
}

// Round 9
// 2272.823 us; speedup vs baseline: 1.0355x; 1.0355x over previous
//
#include <hip/hip_runtime.h>
#include <cstdint>

#define NN 50000
#define EE 800000
#define GG 64

typedef unsigned short u16;
typedef __attribute__((ext_vector_type(8))) short bf16x8;
typedef __attribute__((ext_vector_type(4))) float f32x4;

__device__ __forceinline__ float bf2f(u16 v) { return __uint_as_float(((unsigned)v) << 16); }
__device__ __forceinline__ u16 f2bf(float f) {
  unsigned u = __float_as_uint(f);
  return (u16)((u + 0x7fffu + ((u >> 16) & 1u)) >> 16);
}

__device__ __forceinline__ void gload_lds16(const void* g, void* l) {
  __builtin_amdgcn_global_load_lds(
      (const __attribute__((address_space(1))) void*)g,
      (__attribute__((address_space(3))) void*)l,
      16, 0, 0);
}

__global__ void k_sentinel(float* out) { out[threadIdx.x] = 1e12f; }

// ---------------- merged histograms: in-degree (dst) + out-degree (src) ------
__global__ __launch_bounds__(256) void k_hist(const int* __restrict__ ei,
                                              int* __restrict__ deg,
                                              int* __restrict__ outdeg) {
  int i = blockIdx.x * 256 + threadIdx.x;
  if (i < EE) {
    atomicAdd(&outdeg[ei[i]], 1);
    atomicAdd(&deg[ei[EE + i]], 1);
  }
}

// one block per graph: binary-search boundaries in sorted batch, reduce outdeg.
__global__ __launch_bounds__(256) void k_graph_feats(const int* __restrict__ batch,
                                                     const int* __restrict__ outdeg,
                                                     float* __restrict__ gf) {
  __shared__ int red[256];
  int g = blockIdx.x, tid = threadIdx.x;
  auto lb = [&](int v) {
    int lo = 0, hi = NN;
    while (lo < hi) { int m = (lo + hi) >> 1; if (batch[m] < v) lo = m + 1; else hi = m; }
    return lo;
  };
  int bs = lb(g), be = lb(g + 1);
  int s = 0;
  for (int i = bs + tid; i < be; i += 256) s += outdeg[i];
  red[tid] = s;
  __syncthreads();
  for (int off = 128; off > 0; off >>= 1) {
    if (tid < off) red[tid] += red[tid + off];
    __syncthreads();
  }
  if (tid == 0) {
    gf[g * 2] = logf((float)(be - bs) + 1.f);
    gf[g * 2 + 1] = logf((float)red[0] + 1.f);
  }
}

// ------- router v4 (fp32, 8 nodes/block) + fused encoder output --------------
// Stage-1 is VALU-FMA-bound (13.2 GF fp32, floor ~84us); 18KB LDS keeps
// occupancy ~73% (8 blocks/CU). v5's 32-node variant regressed (r8: 68KB LDS
// -> 19% occupancy) — do not revisit without an occupancy-neutral layout.
__global__ __launch_bounds__(256) void k_router(
    const float* __restrict__ x, const float* __restrict__ encW, const float* __restrict__ encb,
    const int* __restrict__ batch, const float* __restrict__ gf,
    const float* __restrict__ W1, const float* __restrict__ b1,
    const float* __restrict__ W2, const float* __restrict__ b2,
    float* __restrict__ sparse, u16* __restrict__ hb_out) {
  __shared__ __align__(16) float hs_t[258][8];  // k-major: row k holds h[0..7][k]
  __shared__ __align__(16) float rs_t[256][8];
  __shared__ float part2[4][64];
  __shared__ float xv[8][6];
  __shared__ float sf[8][2];
  __shared__ float lg[8][8];
  int tid = threadIdx.x;
  int nb = blockIdx.x * 8;  // NN = 50000 = 6250*8 exact
  if (tid < 48) {
    int r = tid / 6, k = tid % 6;
    xv[r][k] = x[(nb + r) * 6 + k];
  }
  if (tid >= 48 && tid < 56) {
    int r = tid - 48;
    int g = batch[nb + r];
    sf[r][0] = gf[g * 2];
    sf[r][1] = gf[g * 2 + 1];
  }
  __syncthreads();
  {
    float wcol[6];
#pragma unroll
    for (int k = 0; k < 6; ++k) wcol[k] = encW[k * 256 + tid];
    float bb = encb[tid];
#pragma unroll
    for (int r = 0; r < 8; ++r) {
      float s = bb;
#pragma unroll
      for (int k = 0; k < 6; ++k) s += xv[r][k] * wcol[k];
      float h = fmaxf(s, 0.f);
      hs_t[tid][r] = h;
      hb_out[(nb + r) * 256 + tid] = f2bf(h);  // fused encoder output
    }
  }
  if (tid < 16) {  // rows 256,257 = size feats
    int r = tid >> 1, c = tid & 1;
    hs_t[256 + c][r] = sf[r][c];
  }
  __syncthreads();
  float acc[8];
  {
    float bb = b1[tid];
#pragma unroll
    for (int r = 0; r < 8; ++r) acc[r] = bb;
  }
  int k = 0;
#pragma unroll 4
  for (; k < 256; ++k) {
    float w = W1[k * 256 + tid];
    float4 ha = *(const float4*)&hs_t[k][0];  // wave-uniform addr -> broadcast
    float4 hb4 = *(const float4*)&hs_t[k][4];
    acc[0] += ha.x * w; acc[1] += ha.y * w; acc[2] += ha.z * w; acc[3] += ha.w * w;
    acc[4] += hb4.x * w; acc[5] += hb4.y * w; acc[6] += hb4.z * w; acc[7] += hb4.w * w;
  }
  for (; k < 258; ++k) {
    float w = W1[k * 256 + tid];
    float4 ha = *(const float4*)&hs_t[k][0];
    float4 hb4 = *(const float4*)&hs_t[k][4];
    acc[0] += ha.x * w; acc[1] += ha.y * w; acc[2] += ha.z * w; acc[3] += ha.w * w;
    acc[4] += hb4.x * w; acc[5] += hb4.y * w; acc[6] += hb4.z * w; acc[7] += hb4.w * w;
  }
#pragma unroll
  for (int r = 0; r < 8; ++r) rs_t[tid][r] = fmaxf(acc[r], 0.f);
  __syncthreads();
  {  // stage 2: all 256 threads; pair=(r,e)=tid&63, k-part=tid>>6
    int pr = tid & 63, pt = tid >> 6;
    int r = pr >> 3, e = pr & 7;
    float s = 0.f;
    int kk0 = pt * 64;
#pragma unroll 4
    for (int kk = kk0; kk < kk0 + 64; ++kk) s += rs_t[kk][r] * W2[kk * 8 + e];
    part2[pt][pr] = s;
  }
  __syncthreads();
  if (tid < 64) {
    int r = tid >> 3, e = tid & 7;
    lg[r][e] = b2[e] + part2[0][tid] + part2[1][tid] + part2[2][tid] + part2[3][tid];
  }
  __syncthreads();
  if (tid < 8) {
    int node = nb + tid;
    {
      float v1 = lg[tid][0];
      int j1 = 0;
#pragma unroll
      for (int j = 1; j < 8; ++j) {
        float v = lg[tid][j];
        if (v > v1) { v1 = v; j1 = j; }
      }
      float v2 = -1e30f;
      int j2 = 0;
#pragma unroll
      for (int j = 0; j < 8; ++j) {
        if (j == j1) continue;
        float v = lg[tid][j];
        if (v > v2) { v2 = v; j2 = j; }
      }
      float ex = expf(v2 - v1);
      float wa = 1.f / (1.f + ex), wb = ex / (1.f + ex);
      float* sp = sparse + node * 8;
#pragma unroll
      for (int j = 0; j < 8; ++j) sp[j] = 0.f;
      sp[j1] = wa;
      sp[j2] = wb;
    }
  }
}

// ---------------- CSR build (by dst) -----------------------------------------
__global__ __launch_bounds__(1024) void k_scan(const int* __restrict__ deg,
                                               int* __restrict__ rowptr) {
  __shared__ int tmp[1024];
  __shared__ int carry;
  if (threadIdx.x == 0) { carry = 0; rowptr[0] = 0; }
  __syncthreads();
  for (int base = 0; base < NN; base += 1024) {
    int i = base + threadIdx.x;
    int v = (i < NN) ? deg[i] : 0;
    tmp[threadIdx.x] = v;
    __syncthreads();
    for (int off = 1; off < 1024; off <<= 1) {
      int t = (threadIdx.x >= off) ? tmp[threadIdx.x - off] : 0;
      __syncthreads();
      tmp[threadIdx.x] += t;
      __syncthreads();
    }
    if (i < NN) rowptr[i + 1] = carry + tmp[threadIdx.x];
    int last = tmp[1023];
    __syncthreads();
    if (threadIdx.x == 0) carry += last;
    __syncthreads();
  }
}

__global__ __launch_bounds__(256) void k_fill(const int* __restrict__ ei,
                                              const int* __restrict__ rowptr,
                                              int* __restrict__ cursor, int* __restrict__ csrc) {
  int i = blockIdx.x * 256 + threadIdx.x;
  if (i < EE) {
    int s = ei[i], d = ei[EE + i];
    int pos = atomicAdd(&cursor[d], 1);
    csrc[rowptr[d] + pos] = s;
  }
}

// -------- SpMM, plain layout (layer-0 shared agg): wave per dst --------------
__global__ __launch_bounds__(256) void k_spmm256(
    const int* __restrict__ rowptr, const int* __restrict__ csrc,
    const u16* __restrict__ X, u16* __restrict__ Y) {
  int wave = threadIdx.x >> 6, lane = threadIdx.x & 63;
  int d = blockIdx.x * 4 + wave;
  if (d >= NN) return;
  int s0 = rowptr[d], s1 = rowptr[d + 1];
  int c4 = lane * 4;
  float a0 = 0.f, a1 = 0.f, a2 = 0.f, a3 = 0.f;
  int i = s0;
  for (; i + 4 <= s1; i += 4) {
    int sa = csrc[i], sb = csrc[i + 1], sc = csrc[i + 2], sd = csrc[i + 3];
    ushort4 va = *(const ushort4*)(X + sa * 256 + c4);
    ushort4 vb = *(const ushort4*)(X + sb * 256 + c4);
    ushort4 vc = *(const ushort4*)(X + sc * 256 + c4);
    ushort4 vd = *(const ushort4*)(X + sd * 256 + c4);
    a0 += bf2f(va.x) + bf2f(vb.x) + bf2f(vc.x) + bf2f(vd.x);
    a1 += bf2f(va.y) + bf2f(vb.y) + bf2f(vc.y) + bf2f(vd.y);
    a2 += bf2f(va.z) + bf2f(vb.z) + bf2f(vc.z) + bf2f(vd.z);
    a3 += bf2f(va.w) + bf2f(vb.w) + bf2f(vc.w) + bf2f(vd.w);
  }
  for (; i < s1; ++i) {
    int sa = csrc[i];
    ushort4 va = *(const ushort4*)(X + sa * 256 + c4);
    a0 += bf2f(va.x);
    a1 += bf2f(va.y);
    a2 += bf2f(va.z);
    a3 += bf2f(va.w);
  }
  ushort4 o;
  o.x = f2bf(a0); o.y = f2bf(a1); o.z = f2bf(a2); o.w = f2bf(a3);
  *(ushort4*)(Y + d * 256 + c4) = o;
}

// -------- SpMM, expert-interleaved: block per dst; rs/4 threads (<=256) ------
__global__ __launch_bounds__(256) void k_spmm_intl(
    const int* __restrict__ rowptr, const int* __restrict__ csrc,
    const u16* __restrict__ X, u16* __restrict__ Y, int rs) {
  int d = blockIdx.x;
  int tid = threadIdx.x;
  if (tid * 4 >= rs) return;
  int s0 = rowptr[d], s1 = rowptr[d + 1];
  int c4 = tid * 4;
  float a0 = 0.f, a1 = 0.f, a2 = 0.f, a3 = 0.f;
  int i = s0;
  for (; i + 4 <= s1; i += 4) {
    int sa = csrc[i], sb = csrc[i + 1], sc = csrc[i + 2], sd = csrc[i + 3];
    ushort4 va = *(const ushort4*)(X + (size_t)sa * rs + c4);
    ushort4 vb = *(const ushort4*)(X + (size_t)sb * rs + c4);
    ushort4 vc = *(const ushort4*)(X + (size_t)sc * rs + c4);
    ushort4 vd = *(const ushort4*)(X + (size_t)sd * rs + c4);
    a0 += bf2f(va.x) + bf2f(vb.x) + bf2f(vc.x) + bf2f(vd.x);
    a1 += bf2f(va.y) + bf2f(vb.y) + bf2f(vc.y) + bf2f(vd.y);
    a2 += bf2f(va.z) + bf2f(vb.z) + bf2f(vc.z) + bf2f(vd.z);
    a3 += bf2f(va.w) + bf2f(vb.w) + bf2f(vc.w) + bf2f(vd.w);
  }
  for (; i < s1; ++i) {
    int sa = csrc[i];
    ushort4 va = *(const ushort4*)(X + (size_t)sa * rs + c4);
    a0 += bf2f(va.x);
    a1 += bf2f(va.y);
    a2 += bf2f(va.z);
    a3 += bf2f(va.w);
  }
  ushort4 o;
  o.x = f2bf(a0); o.y = f2bf(a1); o.z = f2bf(a2); o.w = f2bf(a3);
  *(ushort4*)(Y + (size_t)d * rs + c4) = o;
}

// ------------- weight transpose+bf16 (both stacks): W[m][k][j] -> Wt[m][j][k] -
__global__ __launch_bounds__(256) void k_transpose2(const float* __restrict__ Wr,
                                                    const float* __restrict__ Wn,
                                                    u16* __restrict__ WrT,
                                                    u16* __restrict__ WnT) {
  int idx = blockIdx.x * 256 + threadIdx.x;
  if (idx >= 24 * 65536) return;
  int m = idx >> 16, rem = idx & 65535;
  int k = rem >> 8, j = rem & 255;
  int o = (m << 16) + (j << 8) + k;
  WrT[o] = f2bf(Wr[idx]);
  WnT[o] = f2bf(Wn[idx]);
}

// ---------------- fused dual-source MFMA GEMM (expert-batched, strided) ------
// Round-6 structure (best measured): stage-early + vmcnt(3) + 2 barriers/step.
__global__ __launch_bounds__(512) void k_gemm(
    const u16* __restrict__ X1b, size_t x1gs, int x1rs,
    const u16* __restrict__ X2b, size_t x2gs, int x2rs,
    const u16* __restrict__ W1tb, const u16* __restrict__ W2tb, size_t wst,
    const float* __restrict__ biasb, size_t bst,
    u16* __restrict__ Yb, size_t ygs, int yrs, int relu,
    const float* __restrict__ oWr, const float* __restrict__ oWn, int e0_base,
    float* __restrict__ Y4self, float* __restrict__ Y4nb, int do_out) {
  __shared__ __align__(16) char smem[49152];  // A dbuf 16KB | B dbuf 32KB
  int g = blockIdx.y;
  const u16* X1 = X1b + (size_t)g * x1gs;
  const u16* X2 = X2b + (size_t)g * x2gs;
  const u16* W1t = W1tb + (size_t)g * wst;
  const u16* W2t = W2tb + (size_t)g * wst;
  const float* bias = biasb + (size_t)g * bst;
  u16* Y = Yb + (size_t)g * ygs;
  int tid = threadIdx.x;
  int wave = tid >> 6, lane = tid & 63;
  int l15 = lane & 15, l4 = lane >> 4;
  int m0 = blockIdx.x * 128;
  int wr = wave >> 2, wc = wave & 3;
  const f32x4 fz = {0.f, 0.f, 0.f, 0.f};
  f32x4 acc[4][4];
#pragma unroll
  for (int a = 0; a < 4; ++a)
#pragma unroll
    for (int b = 0; b < 4; ++b) acc[a][b] = fz;

  auto stage = [&](int t) {
    const u16* xs = (t < 8) ? X1 : X2;
    int xrs = (t < 8) ? x1rs : x2rs;
    const u16* wsrc = (t < 8) ? W1t : W2t;
    int kb = (t & 7) * 32;
    int half = t & 1;
    {
      int flat = wave * 1024 + lane * 16;
      int row = flat >> 6, colb = flat & 63;
      int scol = colb ^ (((row >> 1) & 3) << 4);  // inverse-swizzle the SOURCE
      int gr = m0 + row;
      if (gr > NN - 1) gr = NN - 1;
      gload_lds16(xs + (size_t)gr * xrs + kb + (scol >> 1), smem + half * 8192 + flat);
    }
#pragma unroll
    for (int q = 0; q < 2; ++q) {
      int flat = q * 8192 + wave * 1024 + lane * 16;
      int row = flat >> 6, colb = flat & 63;
      int scol = colb ^ (((row >> 1) & 3) << 4);
      gload_lds16(wsrc + row * 256 + kb + (scol >> 1), smem + 16384 + half * 16384 + flat);
    }
  };

  stage(0);
  for (int kt = 0; kt < 16; ++kt) {
    if (kt < 15) {
      stage(kt + 1);
      asm volatile("s_waitcnt vmcnt(3)" ::: "memory");  // tile-kt loads landed
    } else {
      asm volatile("s_waitcnt vmcnt(0)" ::: "memory");
    }
    __builtin_amdgcn_sched_barrier(0);
    __builtin_amdgcn_s_barrier();
    __builtin_amdgcn_sched_barrier(0);
    const char* Ab = smem + (kt & 1) * 8192;
    const char* Bb = smem + 16384 + (kt & 1) * 16384;
    bf16x8 af[4], bfv[4];
#pragma unroll
    for (int mi = 0; mi < 4; ++mi) {
      int r = wr * 64 + mi * 16 + l15;
      af[mi] = *(const bf16x8*)(Ab + r * 64 + ((l4 * 16) ^ (((r >> 1) & 3) << 4)));
    }
#pragma unroll
    for (int nj = 0; nj < 4; ++nj) {
      int c = wc * 64 + nj * 16 + l15;
      bfv[nj] = *(const bf16x8*)(Bb + c * 64 + ((l4 * 16) ^ (((c >> 1) & 3) << 4)));
    }
#pragma unroll
    for (int mi = 0; mi < 4; ++mi)
#pragma unroll
      for (int nj = 0; nj < 4; ++nj)
        acc[mi][nj] =
            __builtin_amdgcn_mfma_f32_16x16x32_bf16(af[mi], bfv[nj], acc[mi][nj], 0, 0, 0);
    __builtin_amdgcn_sched_barrier(0);
    __builtin_amdgcn_s_barrier();
  }

  if (!do_out) {
    // epilogue: C/D map col=lane&15, row=(lane>>4)*4+reg  [m89-verified]
#pragma unroll
    for (int mi = 0; mi < 4; ++mi) {
      int rbase = m0 + wr * 64 + mi * 16 + l4 * 4;
#pragma unroll
      for (int nj = 0; nj < 4; ++nj) {
        int col = wc * 64 + nj * 16 + l15;
        float bv = bias[col];
#pragma unroll
        for (int r2 = 0; r2 < 4; ++r2) {
          int row = rbase + r2;
          if (row < NN) {
            float v = acc[mi][nj][r2] + bv;
            if (relu) v = fmaxf(v, 0.f);
            Y[(size_t)row * yrs + col] = f2bf(v);
          }
        }
      }
    }
  } else {
    // fused out-projection: he2 = relu(acc+bias); Y4self/nb = he2 @ {oWr,oWn}
    int eabs = e0_base + g;
    const float2* wr2p = (const float2*)(oWr + (size_t)eabs * 512);
    const float2* wn2p = (const float2*)(oWn + (size_t)eabs * 512);
    float bv[4]; float2 wa[4], wb[4];
#pragma unroll
    for (int nj = 0; nj < 4; ++nj) {
      int col = wc * 64 + nj * 16 + l15;
      bv[nj] = bias[col];
      wa[nj] = wr2p[col];
      wb[nj] = wn2p[col];
    }
    float* y4red = (float*)smem;  // post-barrier LDS reuse
#pragma unroll
    for (int mi = 0; mi < 4; ++mi) {
#pragma unroll
      for (int r2 = 0; r2 < 4; ++r2) {
        float p0 = 0.f, p1 = 0.f, p2 = 0.f, p3 = 0.f;
#pragma unroll
        for (int nj = 0; nj < 4; ++nj) {
          float v = fmaxf(acc[mi][nj][r2] + bv[nj], 0.f);
          p0 += v * wa[nj].x; p1 += v * wa[nj].y;
          p2 += v * wb[nj].x; p3 += v * wb[nj].y;
        }
#pragma unroll
        for (int off2 = 1; off2 < 16; off2 <<= 1) {
          p0 += __shfl_xor(p0, off2); p1 += __shfl_xor(p1, off2);
          p2 += __shfl_xor(p2, off2); p3 += __shfl_xor(p3, off2);
        }
        if (l15 == 0) {
          int lr = wr * 64 + mi * 16 + l4 * 4 + r2;
          float* q = y4red + (lr * 4 + wc) * 4;
          q[0] = p0; q[1] = p1; q[2] = p2; q[3] = p3;
        }
      }
    }
    __syncthreads();
    if (tid < 128) {
      int row = m0 + tid;
      if (row < NN) {
        float s0 = 0.f, s1 = 0.f, n0 = 0.f, n1 = 0.f;
#pragma unroll
        for (int w2 = 0; w2 < 4; ++w2) {
          const float* q = y4red + (tid * 4 + w2) * 4;
          s0 += q[0]; s1 += q[1]; n0 += q[2]; n1 += q[3];
        }
        Y4self[row * 16 + eabs * 2] = s0;
        Y4self[row * 16 + eabs * 2 + 1] = s1;
        Y4nb[row * 16 + eabs * 2] = n0;
        Y4nb[row * 16 + eabs * 2 + 1] = n1;
      }
    }
  }
}

// ---------------- single-pass combine over all 8 experts ---------------------
__global__ __launch_bounds__(256) void k_combine(
    const int* __restrict__ rowptr, const int* __restrict__ csrc,
    const float* __restrict__ Y4self, const float* __restrict__ Y4nb,
    const float* __restrict__ sparse, const float* __restrict__ ob,
    float* __restrict__ out) {
  int t = blockIdx.x * 256 + threadIdx.x;
  int d = t >> 3, e = t & 7;
  if (d >= NN) return;
  float s0 = Y4self[d * 16 + e * 2], s1 = Y4self[d * 16 + e * 2 + 1];
  float n0 = 0.f, n1 = 0.f;
  for (int i = rowptr[d]; i < rowptr[d + 1]; ++i) {
    int s = csrc[i];
    float2 v = *(const float2*)(Y4nb + s * 16 + e * 2);
    n0 += v.x;
    n1 += v.y;
  }
  float w = sparse[d * 8 + e];
  float t0 = w * (s0 + n0 + ob[e * 2]);
  float t1 = w * (s1 + n1 + ob[e * 2 + 1]);
  t0 += __shfl_xor(t0, 1); t1 += __shfl_xor(t1, 1);
  t0 += __shfl_xor(t0, 2); t1 += __shfl_xor(t1, 2);
  t0 += __shfl_xor(t0, 4); t1 += __shfl_xor(t1, 4);
  if (e == 0) {
    out[d * 2] = t0;
    out[d * 2 + 1] = t1;
  }
}

extern "C" void kernel_launch(void* const* d_in, const int* in_sizes, int n_in,
                              void* d_out, int out_size, void* d_ws, size_t ws_size,
                              hipStream_t stream) {
  const float* x = (const float*)d_in[0];
  const int* ei = (const int*)d_in[1];
  const int* batch = (const int*)d_in[2];
  const float* enc_W = (const float*)d_in[3];
  const float* enc_b = (const float*)d_in[4];
  const float* rW1 = (const float*)d_in[5];
  const float* rb1 = (const float*)d_in[6];
  const float* rW2 = (const float*)d_in[7];
  const float* rb2 = (const float*)d_in[8];
  const float* hid_Wr = (const float*)d_in[9];
  const float* hid_Wn = (const float*)d_in[10];
  const float* hid_b = (const float*)d_in[11];
  const float* out_Wr = (const float*)d_in[12];
  const float* out_Wn = (const float*)d_in[13];
  const float* out_b = (const float*)d_in[14];
  float* out = (float*)d_out;

  char* ws = (char*)d_ws;
  size_t off = 0;
  auto alloc = [&](size_t bytes) -> void* {
    void* p = ws + off;
    off = (off + bytes + 511) & ~(size_t)511;
    return p;
  };
  const size_t HBYTES = (size_t)NN * 256 * 2;      // 25.6 MB
  u16* hb = (u16*)alloc(HBYTES);
  u16* agg0 = (u16*)alloc(HBYTES);
  u16* WrT = (u16*)alloc((size_t)24 * 65536 * 2);  // 3.15 MB
  u16* WnT = (u16*)alloc((size_t)24 * 65536 * 2);
  // contiguous zero region: deg | cursor | outdeg
  int* deg = (int*)alloc((size_t)NN * 4);
  int* cursor = (int*)alloc((size_t)NN * 4);
  int* outdeg = (int*)alloc((size_t)NN * 4);
  size_t zero_bytes = (size_t)((char*)(outdeg + NN) - (char*)deg);
  int* rowptr = (int*)alloc((size_t)(NN + 1) * 4);
  int* csrc = (int*)alloc((size_t)EE * 4);  // 3.2 MB
  float* gf = (float*)alloc(GG * 2 * 4);
  float* sparse = (float*)alloc((size_t)NN * 8 * 4);   // 1.6 MB
  float* Y4self = (float*)alloc((size_t)NN * 16 * 4);  // 3.2 MB
  float* Y4nb = (float*)alloc((size_t)NN * 16 * 4);    // 3.2 MB

  // Expert group size: he+agg pair = 51.2 MB per expert. Cap at 4 (L3 comfort;
  // grp=8 has no byte-reduction theory and was never isolated — r8 lesson).
  size_t rem = (ws_size > off) ? ws_size - off : 0;
  size_t per = 2 * HBYTES + 2048;
  int grp = (rem >= 4 * per) ? 4 : (rem >= 2 * per) ? 2 : (rem >= per) ? 1 : 0;
  if (grp == 0) {
    k_sentinel<<<1, 2, 0, stream>>>(out);
    return;
  }
  u16* heb = (u16*)alloc((size_t)grp * HBYTES);   // interleaved [node][g][256]
  u16* aggb = (u16*)alloc((size_t)grp * HBYTES);  // interleaved [node][g][256]
  const int RS = grp * 256;                       // interleaved row stride (elems)

  hipMemsetAsync(deg, 0, zero_bytes, stream);

  k_transpose2<<<(24 * 65536 + 255) / 256, 256, 0, stream>>>(hid_Wr, hid_Wn, WrT, WnT);
  k_hist<<<(EE + 255) / 256, 256, 0, stream>>>(ei, deg, outdeg);
  k_graph_feats<<<GG, 256, 0, stream>>>(batch, outdeg, gf);
  k_scan<<<1, 1024, 0, stream>>>(deg, rowptr);
  k_fill<<<(EE + 255) / 256, 256, 0, stream>>>(ei, rowptr, cursor, csrc);
  k_router<<<NN / 8, 256, 0, stream>>>(x, enc_W, enc_b, batch, gf, rW1, rb1, rW2, rb2,
                                       sparse, hb);

  const int GX = (NN + 127) / 128;  // 391 gemm blocks per expert

  // shared layer-0 aggregation of h (identical input for every expert)
  k_spmm256<<<(NN + 3) / 4, 256, 0, stream>>>(rowptr, csrc, hb, agg0);
  for (int e0 = 0; e0 < 8; e0 += grp) {
    // layer 0 (batched over grp experts): plain-layout inputs -> interleaved Y
    k_gemm<<<dim3(GX, grp), 512, 0, stream>>>(
        hb, 0, 256, agg0, 0, 256, WrT + e0 * 65536, WnT + e0 * 65536, 65536,
        hid_b + e0 * 256, 256, heb, 256, RS, 1, nullptr, nullptr, 0, nullptr, nullptr, 0);
    // layer 1 (interleaved throughout)
    k_spmm_intl<<<NN, RS / 4, 0, stream>>>(rowptr, csrc, heb, aggb, RS);
    k_gemm<<<dim3(GX, grp), 512, 0, stream>>>(
        heb, 256, RS, aggb, 256, RS, WrT + (8 + e0) * 65536, WnT + (8 + e0) * 65536, 65536,
        hid_b + (8 + e0) * 256, 256, heb, 256, RS, 1, nullptr, nullptr, 0, nullptr, nullptr, 0);
    // layer 2 + fused out-projection (he2 never materialized)
    k_spmm_intl<<<NN, RS / 4, 0, stream>>>(rowptr, csrc, heb, aggb, RS);
    k_gemm<<<dim3(GX, grp), 512, 0, stream>>>(
        heb, 256, RS, aggb, 256, RS, WrT + (16 + e0) * 65536, WnT + (16 + e0) * 65536, 65536,
        hid_b + (16 + e0) * 256, 256, nullptr, 0, 256, 1, out_Wr, out_Wn, e0,
        Y4self, Y4nb, 1);
  }
  k_combine<<<(NN * 8 + 255) / 256, 256, 0, stream>>>(rowptr, csrc, Y4self, Y4nb, sparse,
                                                      out_b, out);
}

// Round 10
// 2149.858 us; speedup vs baseline: 1.0947x; 1.0572x over previous
//
#include <hip/hip_runtime.h>
#include <cstdint>

#define NN 50000
#define EE 800000
#define GG 64

typedef unsigned short u16;
typedef __attribute__((ext_vector_type(8))) short bf16x8;
typedef __attribute__((ext_vector_type(4))) float f32x4;

__device__ __forceinline__ float bf2f(u16 v) { return __uint_as_float(((unsigned)v) << 16); }
__device__ __forceinline__ u16 f2bf(float f) {
  unsigned u = __float_as_uint(f);
  return (u16)((u + 0x7fffu + ((u >> 16) & 1u)) >> 16);
}

__device__ __forceinline__ void gload_lds16(const void* g, void* l) {
  __builtin_amdgcn_global_load_lds(
      (const __attribute__((address_space(1))) void*)g,
      (__attribute__((address_space(3))) void*)l,
      16, 0, 0);
}

__global__ void k_sentinel(float* out) { out[threadIdx.x] = 1e12f; }

// ---- prep1: weight transpose+bf16 (6144 blocks) ∥ histograms+epos (3125) ----
__global__ __launch_bounds__(256) void k_prep1(
    const float* __restrict__ Wr, const float* __restrict__ Wn,
    u16* __restrict__ WrT, u16* __restrict__ WnT,
    const int* __restrict__ ei, int* __restrict__ deg, int* __restrict__ outdeg,
    int* __restrict__ epos) {
  int b = blockIdx.x, tid = threadIdx.x;
  if (b < 6144) {  // transpose: W[m][k][j] -> Wt[m][j][k]
    int idx = b * 256 + tid;  // 6144*256 == 24*65536 exactly
    int m = idx >> 16, rem = idx & 65535;
    int k = rem >> 8, j = rem & 255;
    int o = (m << 16) + (j << 8) + k;
    WrT[o] = f2bf(Wr[idx]);
    WnT[o] = f2bf(Wn[idx]);
  } else {  // histograms; epos = insertion slot for atomic-free fill later
    int i = (b - 6144) * 256 + tid;
    if (i < EE) {
      atomicAdd(&outdeg[ei[i]], 1);
      epos[i] = atomicAdd(&deg[ei[EE + i]], 1);
    }
  }
}

// ---- prep2: graph size feats (64 blocks) ∥ scan level-1 (196 blocks) --------
__global__ __launch_bounds__(256) void k_prep2(
    const int* __restrict__ batch, const int* __restrict__ outdeg,
    float* __restrict__ gf, const int* __restrict__ deg,
    int* __restrict__ lpre, int* __restrict__ bsum) {
  int b = blockIdx.x, tid = threadIdx.x;
  if (b < GG) {  // per-graph node/edge counts via binary search + outdeg reduce
    __shared__ int red[256];
    int g = b;
    auto lb = [&](int v) {
      int lo = 0, hi = NN;
      while (lo < hi) { int m = (lo + hi) >> 1; if (batch[m] < v) lo = m + 1; else hi = m; }
      return lo;
    };
    int bs = lb(g), be = lb(g + 1);
    int s = 0;
    for (int i = bs + tid; i < be; i += 256) s += outdeg[i];
    red[tid] = s;
    __syncthreads();
    for (int off = 128; off > 0; off >>= 1) {
      if (tid < off) red[tid] += red[tid + off];
      __syncthreads();
    }
    if (tid == 0) {
      gf[g * 2] = logf((float)(be - bs) + 1.f);
      gf[g * 2 + 1] = logf((float)red[0] + 1.f);
    }
  } else {  // scan1: per-256-chunk exclusive prefix of deg + chunk sum
    __shared__ int tmp[256];
    int blk = b - GG;
    int i = blk * 256 + tid;
    int v = (i < NN) ? deg[i] : 0;
    tmp[tid] = v;
    __syncthreads();
    for (int off = 1; off < 256; off <<= 1) {
      int t = (tid >= off) ? tmp[tid - off] : 0;
      __syncthreads();
      tmp[tid] += t;
      __syncthreads();
    }
    if (i < NN) lpre[i] = tmp[tid] - v;  // exclusive within chunk
    if (tid == 255) bsum[blk] = tmp[255];
  }
}

// ---- scan level-2: exclusive scan of 196 chunk sums (1 block) ---------------
__global__ __launch_bounds__(256) void k_scan2(const int* __restrict__ bsum,
                                               int* __restrict__ boff) {
  __shared__ int tmp[256];
  int tid = threadIdx.x;
  int v = (tid < 196) ? bsum[tid] : 0;
  tmp[tid] = v;
  __syncthreads();
  for (int off = 1; off < 256; off <<= 1) {
    int t = (tid >= off) ? tmp[tid - off] : 0;
    __syncthreads();
    tmp[tid] += t;
    __syncthreads();
  }
  if (tid < 196) boff[tid] = tmp[tid] - v;
}

// ---- prep3: router (6250) ∥ atomic-free fill (3125) ∥ rowptr write (196) ----
// Fill (~20us) and rowptr hide entirely under the 140us router.
__global__ __launch_bounds__(256) void k_prep3(
    const float* __restrict__ x, const float* __restrict__ encW, const float* __restrict__ encb,
    const int* __restrict__ batch, const float* __restrict__ gf,
    const float* __restrict__ W1, const float* __restrict__ b1,
    const float* __restrict__ W2, const float* __restrict__ b2,
    float* __restrict__ sparse, u16* __restrict__ hb_out,
    const int* __restrict__ ei, const int* __restrict__ epos,
    const int* __restrict__ lpre, const int* __restrict__ boff,
    const int* __restrict__ deg, int* __restrict__ csrc, int* __restrict__ rowptr) {
  __shared__ __align__(16) float hs_t[258][8];
  __shared__ __align__(16) float rs_t[256][8];
  __shared__ float part2[4][64];
  __shared__ float xv[8][6];
  __shared__ float sf[8][2];
  __shared__ float lg[8][8];
  int b = blockIdx.x, tid = threadIdx.x;
  if (b >= 6250) {
    if (b < 6250 + 3125) {  // fill: pure scatter, no atomics
      int i = (b - 6250) * 256 + tid;
      if (i < EE) {
        int s = ei[i], d = ei[EE + i];
        csrc[lpre[d] + boff[d >> 8] + epos[i]] = s;
      }
    } else {  // rowptr materialization (for spmm/combine)
      int j = (b - 6250 - 3125) * 256 + tid;
      if (j < NN) rowptr[j + 1] = lpre[j] + deg[j] + boff[j >> 8];
      if (j == 0) rowptr[0] = 0;
    }
    return;
  }
  // ---------------- router v4 (unchanged arithmetic) ----------------
  int nb = b * 8;  // NN = 50000 = 6250*8 exact
  if (tid < 48) {
    int r = tid / 6, k = tid % 6;
    xv[r][k] = x[(nb + r) * 6 + k];
  }
  if (tid >= 48 && tid < 56) {
    int r = tid - 48;
    int g = batch[nb + r];
    sf[r][0] = gf[g * 2];
    sf[r][1] = gf[g * 2 + 1];
  }
  __syncthreads();
  {
    float wcol[6];
#pragma unroll
    for (int k = 0; k < 6; ++k) wcol[k] = encW[k * 256 + tid];
    float bb = encb[tid];
#pragma unroll
    for (int r = 0; r < 8; ++r) {
      float s = bb;
#pragma unroll
      for (int k = 0; k < 6; ++k) s += xv[r][k] * wcol[k];
      float h = fmaxf(s, 0.f);
      hs_t[tid][r] = h;
      hb_out[(nb + r) * 256 + tid] = f2bf(h);
    }
  }
  if (tid < 16) {
    int r = tid >> 1, c = tid & 1;
    hs_t[256 + c][r] = sf[r][c];
  }
  __syncthreads();
  float acc[8];
  {
    float bb = b1[tid];
#pragma unroll
    for (int r = 0; r < 8; ++r) acc[r] = bb;
  }
  int k = 0;
#pragma unroll 4
  for (; k < 256; ++k) {
    float w = W1[k * 256 + tid];
    float4 ha = *(const float4*)&hs_t[k][0];
    float4 hb4 = *(const float4*)&hs_t[k][4];
    acc[0] += ha.x * w; acc[1] += ha.y * w; acc[2] += ha.z * w; acc[3] += ha.w * w;
    acc[4] += hb4.x * w; acc[5] += hb4.y * w; acc[6] += hb4.z * w; acc[7] += hb4.w * w;
  }
  for (; k < 258; ++k) {
    float w = W1[k * 256 + tid];
    float4 ha = *(const float4*)&hs_t[k][0];
    float4 hb4 = *(const float4*)&hs_t[k][4];
    acc[0] += ha.x * w; acc[1] += ha.y * w; acc[2] += ha.z * w; acc[3] += ha.w * w;
    acc[4] += hb4.x * w; acc[5] += hb4.y * w; acc[6] += hb4.z * w; acc[7] += hb4.w * w;
  }
#pragma unroll
  for (int r = 0; r < 8; ++r) rs_t[tid][r] = fmaxf(acc[r], 0.f);
  __syncthreads();
  {
    int pr = tid & 63, pt = tid >> 6;
    int r = pr >> 3, e = pr & 7;
    float s = 0.f;
    int kk0 = pt * 64;
#pragma unroll 4
    for (int kk = kk0; kk < kk0 + 64; ++kk) s += rs_t[kk][r] * W2[kk * 8 + e];
    part2[pt][pr] = s;
  }
  __syncthreads();
  if (tid < 64) {
    int r = tid >> 3, e = tid & 7;
    lg[r][e] = b2[e] + part2[0][tid] + part2[1][tid] + part2[2][tid] + part2[3][tid];
  }
  __syncthreads();
  if (tid < 8) {
    int node = nb + tid;
    float v1 = lg[tid][0];
    int j1 = 0;
#pragma unroll
    for (int j = 1; j < 8; ++j) {
      float v = lg[tid][j];
      if (v > v1) { v1 = v; j1 = j; }
    }
    float v2 = -1e30f;
    int j2 = 0;
#pragma unroll
    for (int j = 0; j < 8; ++j) {
      if (j == j1) continue;
      float v = lg[tid][j];
      if (v > v2) { v2 = v; j2 = j; }
    }
    float ex = expf(v2 - v1);
    float wa = 1.f / (1.f + ex), wb = ex / (1.f + ex);
    float* sp = sparse + node * 8;
#pragma unroll
    for (int j = 0; j < 8; ++j) sp[j] = 0.f;
    sp[j1] = wa;
    sp[j2] = wb;
  }
}

// -------- SpMM, plain layout (layer-0 shared agg): wave per dst --------------
__global__ __launch_bounds__(256) void k_spmm256(
    const int* __restrict__ rowptr, const int* __restrict__ csrc,
    const u16* __restrict__ X, u16* __restrict__ Y) {
  int wave = threadIdx.x >> 6, lane = threadIdx.x & 63;
  int d = blockIdx.x * 4 + wave;
  if (d >= NN) return;
  int s0 = rowptr[d], s1 = rowptr[d + 1];
  int c4 = lane * 4;
  float a0 = 0.f, a1 = 0.f, a2 = 0.f, a3 = 0.f;
  int i = s0;
  for (; i + 4 <= s1; i += 4) {
    int sa = csrc[i], sb = csrc[i + 1], sc = csrc[i + 2], sd = csrc[i + 3];
    ushort4 va = *(const ushort4*)(X + sa * 256 + c4);
    ushort4 vb = *(const ushort4*)(X + sb * 256 + c4);
    ushort4 vc = *(const ushort4*)(X + sc * 256 + c4);
    ushort4 vd = *(const ushort4*)(X + sd * 256 + c4);
    a0 += bf2f(va.x) + bf2f(vb.x) + bf2f(vc.x) + bf2f(vd.x);
    a1 += bf2f(va.y) + bf2f(vb.y) + bf2f(vc.y) + bf2f(vd.y);
    a2 += bf2f(va.z) + bf2f(vb.z) + bf2f(vc.z) + bf2f(vd.z);
    a3 += bf2f(va.w) + bf2f(vb.w) + bf2f(vc.w) + bf2f(vd.w);
  }
  for (; i < s1; ++i) {
    int sa = csrc[i];
    ushort4 va = *(const ushort4*)(X + sa * 256 + c4);
    a0 += bf2f(va.x);
    a1 += bf2f(va.y);
    a2 += bf2f(va.z);
    a3 += bf2f(va.w);
  }
  ushort4 o;
  o.x = f2bf(a0); o.y = f2bf(a1); o.z = f2bf(a2); o.w = f2bf(a3);
  *(ushort4*)(Y + d * 256 + c4) = o;
}

// -------- SpMM, expert-interleaved: block per dst; rs/4 threads (<=256) ------
__global__ __launch_bounds__(256) void k_spmm_intl(
    const int* __restrict__ rowptr, const int* __restrict__ csrc,
    const u16* __restrict__ X, u16* __restrict__ Y, int rs) {
  int d = blockIdx.x;
  int tid = threadIdx.x;
  if (tid * 4 >= rs) return;
  int s0 = rowptr[d], s1 = rowptr[d + 1];
  int c4 = tid * 4;
  float a0 = 0.f, a1 = 0.f, a2 = 0.f, a3 = 0.f;
  int i = s0;
  for (; i + 4 <= s1; i += 4) {
    int sa = csrc[i], sb = csrc[i + 1], sc = csrc[i + 2], sd = csrc[i + 3];
    ushort4 va = *(const ushort4*)(X + (size_t)sa * rs + c4);
    ushort4 vb = *(const ushort4*)(X + (size_t)sb * rs + c4);
    ushort4 vc = *(const ushort4*)(X + (size_t)sc * rs + c4);
    ushort4 vd = *(const ushort4*)(X + (size_t)sd * rs + c4);
    a0 += bf2f(va.x) + bf2f(vb.x) + bf2f(vc.x) + bf2f(vd.x);
    a1 += bf2f(va.y) + bf2f(vb.y) + bf2f(vc.y) + bf2f(vd.y);
    a2 += bf2f(va.z) + bf2f(vb.z) + bf2f(vc.z) + bf2f(vd.z);
    a3 += bf2f(va.w) + bf2f(vb.w) + bf2f(vc.w) + bf2f(vd.w);
  }
  for (; i < s1; ++i) {
    int sa = csrc[i];
    ushort4 va = *(const ushort4*)(X + (size_t)sa * rs + c4);
    a0 += bf2f(va.x);
    a1 += bf2f(va.y);
    a2 += bf2f(va.z);
    a3 += bf2f(va.w);
  }
  ushort4 o;
  o.x = f2bf(a0); o.y = f2bf(a1); o.z = f2bf(a2); o.w = f2bf(a3);
  *(ushort4*)(Y + (size_t)d * rs + c4) = o;
}

// ---------------- fused dual-source MFMA GEMM (expert-batched, strided) ------
// Round-6 structure (best measured): stage-early + vmcnt(3) + 2 barriers/step.
__global__ __launch_bounds__(512) void k_gemm(
    const u16* __restrict__ X1b, size_t x1gs, int x1rs,
    const u16* __restrict__ X2b, size_t x2gs, int x2rs,
    const u16* __restrict__ W1tb, const u16* __restrict__ W2tb, size_t wst,
    const float* __restrict__ biasb, size_t bst,
    u16* __restrict__ Yb, size_t ygs, int yrs, int relu,
    const float* __restrict__ oWr, const float* __restrict__ oWn, int e0_base,
    float* __restrict__ Y4self, float* __restrict__ Y4nb, int do_out) {
  __shared__ __align__(16) char smem[49152];  // A dbuf 16KB | B dbuf 32KB
  int g = blockIdx.y;
  const u16* X1 = X1b + (size_t)g * x1gs;
  const u16* X2 = X2b + (size_t)g * x2gs;
  const u16* W1t = W1tb + (size_t)g * wst;
  const u16* W2t = W2tb + (size_t)g * wst;
  const float* bias = biasb + (size_t)g * bst;
  u16* Y = Yb + (size_t)g * ygs;
  int tid = threadIdx.x;
  int wave = tid >> 6, lane = tid & 63;
  int l15 = lane & 15, l4 = lane >> 4;
  int m0 = blockIdx.x * 128;
  int wr = wave >> 2, wc = wave & 3;
  const f32x4 fz = {0.f, 0.f, 0.f, 0.f};
  f32x4 acc[4][4];
#pragma unroll
  for (int a = 0; a < 4; ++a)
#pragma unroll
    for (int b = 0; b < 4; ++b) acc[a][b] = fz;

  auto stage = [&](int t) {
    const u16* xs = (t < 8) ? X1 : X2;
    int xrs = (t < 8) ? x1rs : x2rs;
    const u16* wsrc = (t < 8) ? W1t : W2t;
    int kb = (t & 7) * 32;
    int half = t & 1;
    {
      int flat = wave * 1024 + lane * 16;
      int row = flat >> 6, colb = flat & 63;
      int scol = colb ^ (((row >> 1) & 3) << 4);  // inverse-swizzle the SOURCE
      int gr = m0 + row;
      if (gr > NN - 1) gr = NN - 1;
      gload_lds16(xs + (size_t)gr * xrs + kb + (scol >> 1), smem + half * 8192 + flat);
    }
#pragma unroll
    for (int q = 0; q < 2; ++q) {
      int flat = q * 8192 + wave * 1024 + lane * 16;
      int row = flat >> 6, colb = flat & 63;
      int scol = colb ^ (((row >> 1) & 3) << 4);
      gload_lds16(wsrc + row * 256 + kb + (scol >> 1), smem + 16384 + half * 16384 + flat);
    }
  };

  stage(0);
  for (int kt = 0; kt < 16; ++kt) {
    if (kt < 15) {
      stage(kt + 1);
      asm volatile("s_waitcnt vmcnt(3)" ::: "memory");  // tile-kt loads landed
    } else {
      asm volatile("s_waitcnt vmcnt(0)" ::: "memory");
    }
    __builtin_amdgcn_sched_barrier(0);
    __builtin_amdgcn_s_barrier();
    __builtin_amdgcn_sched_barrier(0);
    const char* Ab = smem + (kt & 1) * 8192;
    const char* Bb = smem + 16384 + (kt & 1) * 16384;
    bf16x8 af[4], bfv[4];
#pragma unroll
    for (int mi = 0; mi < 4; ++mi) {
      int r = wr * 64 + mi * 16 + l15;
      af[mi] = *(const bf16x8*)(Ab + r * 64 + ((l4 * 16) ^ (((r >> 1) & 3) << 4)));
    }
#pragma unroll
    for (int nj = 0; nj < 4; ++nj) {
      int c = wc * 64 + nj * 16 + l15;
      bfv[nj] = *(const bf16x8*)(Bb + c * 64 + ((l4 * 16) ^ (((c >> 1) & 3) << 4)));
    }
#pragma unroll
    for (int mi = 0; mi < 4; ++mi)
#pragma unroll
      for (int nj = 0; nj < 4; ++nj)
        acc[mi][nj] =
            __builtin_amdgcn_mfma_f32_16x16x32_bf16(af[mi], bfv[nj], acc[mi][nj], 0, 0, 0);
    __builtin_amdgcn_sched_barrier(0);
    __builtin_amdgcn_s_barrier();
  }

  if (!do_out) {
    // epilogue: C/D map col=lane&15, row=(lane>>4)*4+reg  [m89-verified]
#pragma unroll
    for (int mi = 0; mi < 4; ++mi) {
      int rbase = m0 + wr * 64 + mi * 16 + l4 * 4;
#pragma unroll
      for (int nj = 0; nj < 4; ++nj) {
        int col = wc * 64 + nj * 16 + l15;
        float bv = bias[col];
#pragma unroll
        for (int r2 = 0; r2 < 4; ++r2) {
          int row = rbase + r2;
          if (row < NN) {
            float v = acc[mi][nj][r2] + bv;
            if (relu) v = fmaxf(v, 0.f);
            Y[(size_t)row * yrs + col] = f2bf(v);
          }
        }
      }
    }
  } else {
    // fused out-projection: he2 = relu(acc+bias); Y4self/nb = he2 @ {oWr,oWn}
    int eabs = e0_base + g;
    const float2* wr2p = (const float2*)(oWr + (size_t)eabs * 512);
    const float2* wn2p = (const float2*)(oWn + (size_t)eabs * 512);
    float bv[4]; float2 wa[4], wb[4];
#pragma unroll
    for (int nj = 0; nj < 4; ++nj) {
      int col = wc * 64 + nj * 16 + l15;
      bv[nj] = bias[col];
      wa[nj] = wr2p[col];
      wb[nj] = wn2p[col];
    }
    float* y4red = (float*)smem;  // post-barrier LDS reuse
#pragma unroll
    for (int mi = 0; mi < 4; ++mi) {
#pragma unroll
      for (int r2 = 0; r2 < 4; ++r2) {
        float p0 = 0.f, p1 = 0.f, p2 = 0.f, p3 = 0.f;
#pragma unroll
        for (int nj = 0; nj < 4; ++nj) {
          float v = fmaxf(acc[mi][nj][r2] + bv[nj], 0.f);
          p0 += v * wa[nj].x; p1 += v * wa[nj].y;
          p2 += v * wb[nj].x; p3 += v * wb[nj].y;
        }
#pragma unroll
        for (int off2 = 1; off2 < 16; off2 <<= 1) {
          p0 += __shfl_xor(p0, off2); p1 += __shfl_xor(p1, off2);
          p2 += __shfl_xor(p2, off2); p3 += __shfl_xor(p3, off2);
        }
        if (l15 == 0) {
          int lr = wr * 64 + mi * 16 + l4 * 4 + r2;
          float* q = y4red + (lr * 4 + wc) * 4;
          q[0] = p0; q[1] = p1; q[2] = p2; q[3] = p3;
        }
      }
    }
    __syncthreads();
    if (tid < 128) {
      int row = m0 + tid;
      if (row < NN) {
        float s0 = 0.f, s1 = 0.f, n0 = 0.f, n1 = 0.f;
#pragma unroll
        for (int w2 = 0; w2 < 4; ++w2) {
          const float* q = y4red + (tid * 4 + w2) * 4;
          s0 += q[0]; s1 += q[1]; n0 += q[2]; n1 += q[3];
        }
        Y4self[row * 16 + eabs * 2] = s0;
        Y4self[row * 16 + eabs * 2 + 1] = s1;
        Y4nb[row * 16 + eabs * 2] = n0;
        Y4nb[row * 16 + eabs * 2 + 1] = n1;
      }
    }
  }
}

// ---------------- single-pass combine over all 8 experts ---------------------
__global__ __launch_bounds__(256) void k_combine(
    const int* __restrict__ rowptr, const int* __restrict__ csrc,
    const float* __restrict__ Y4self, const float* __restrict__ Y4nb,
    const float* __restrict__ sparse, const float* __restrict__ ob,
    float* __restrict__ out) {
  int t = blockIdx.x * 256 + threadIdx.x;
  int d = t >> 3, e = t & 7;
  if (d >= NN) return;
  float s0 = Y4self[d * 16 + e * 2], s1 = Y4self[d * 16 + e * 2 + 1];
  float n0 = 0.f, n1 = 0.f;
  for (int i = rowptr[d]; i < rowptr[d + 1]; ++i) {
    int s = csrc[i];
    float2 v = *(const float2*)(Y4nb + s * 16 + e * 2);
    n0 += v.x;
    n1 += v.y;
  }
  float w = sparse[d * 8 + e];
  float t0 = w * (s0 + n0 + ob[e * 2]);
  float t1 = w * (s1 + n1 + ob[e * 2 + 1]);
  t0 += __shfl_xor(t0, 1); t1 += __shfl_xor(t1, 1);
  t0 += __shfl_xor(t0, 2); t1 += __shfl_xor(t1, 2);
  t0 += __shfl_xor(t0, 4); t1 += __shfl_xor(t1, 4);
  if (e == 0) {
    out[d * 2] = t0;
    out[d * 2 + 1] = t1;
  }
}

extern "C" void kernel_launch(void* const* d_in, const int* in_sizes, int n_in,
                              void* d_out, int out_size, void* d_ws, size_t ws_size,
                              hipStream_t stream) {
  const float* x = (const float*)d_in[0];
  const int* ei = (const int*)d_in[1];
  const int* batch = (const int*)d_in[2];
  const float* enc_W = (const float*)d_in[3];
  const float* enc_b = (const float*)d_in[4];
  const float* rW1 = (const float*)d_in[5];
  const float* rb1 = (const float*)d_in[6];
  const float* rW2 = (const float*)d_in[7];
  const float* rb2 = (const float*)d_in[8];
  const float* hid_Wr = (const float*)d_in[9];
  const float* hid_Wn = (const float*)d_in[10];
  const float* hid_b = (const float*)d_in[11];
  const float* out_Wr = (const float*)d_in[12];
  const float* out_Wn = (const float*)d_in[13];
  const float* out_b = (const float*)d_in[14];
  float* out = (float*)d_out;

  char* ws = (char*)d_ws;
  size_t off = 0;
  auto alloc = [&](size_t bytes) -> void* {
    void* p = ws + off;
    off = (off + bytes + 511) & ~(size_t)511;
    return p;
  };
  const size_t HBYTES = (size_t)NN * 256 * 2;      // 25.6 MB
  u16* hb = (u16*)alloc(HBYTES);
  u16* agg0 = (u16*)alloc(HBYTES);
  u16* WrT = (u16*)alloc((size_t)24 * 65536 * 2);  // 3.15 MB
  u16* WnT = (u16*)alloc((size_t)24 * 65536 * 2);
  // contiguous zero region: deg | outdeg
  int* deg = (int*)alloc((size_t)NN * 4);
  int* outdeg = (int*)alloc((size_t)NN * 4);
  size_t zero_bytes = (size_t)((char*)(outdeg + NN) - (char*)deg);
  int* rowptr = (int*)alloc((size_t)(NN + 1) * 4);
  int* csrc = (int*)alloc((size_t)EE * 4);  // 3.2 MB
  int* epos = (int*)alloc((size_t)EE * 4);  // 3.2 MB
  int* lpre = (int*)alloc((size_t)NN * 4);
  int* bsum = (int*)alloc(256 * 4);
  int* boff = (int*)alloc(256 * 4);
  float* gf = (float*)alloc(GG * 2 * 4);
  float* sparse = (float*)alloc((size_t)NN * 8 * 4);   // 1.6 MB
  float* Y4self = (float*)alloc((size_t)NN * 16 * 4);  // 3.2 MB
  float* Y4nb = (float*)alloc((size_t)NN * 16 * 4);    // 3.2 MB

  // Expert group size: he+agg pair = 51.2 MB per expert. Cap at 4 (L3 comfort).
  size_t rem = (ws_size > off) ? ws_size - off : 0;
  size_t per = 2 * HBYTES + 2048;
  int grp = (rem >= 4 * per) ? 4 : (rem >= 2 * per) ? 2 : (rem >= per) ? 1 : 0;
  if (grp == 0) {
    k_sentinel<<<1, 2, 0, stream>>>(out);
    return;
  }
  u16* heb = (u16*)alloc((size_t)grp * HBYTES);   // interleaved [node][g][256]
  u16* aggb = (u16*)alloc((size_t)grp * HBYTES);  // interleaved [node][g][256]
  const int RS = grp * 256;                       // interleaved row stride (elems)

  hipMemsetAsync(deg, 0, zero_bytes, stream);

  // prep chain: 4 fused dispatches (was 6 + slower scan)
  k_prep1<<<6144 + 3125, 256, 0, stream>>>(hid_Wr, hid_Wn, WrT, WnT, ei, deg, outdeg, epos);
  k_prep2<<<GG + 196, 256, 0, stream>>>(batch, outdeg, gf, deg, lpre, bsum);
  k_scan2<<<1, 256, 0, stream>>>(bsum, boff);
  k_prep3<<<6250 + 3125 + 196, 256, 0, stream>>>(x, enc_W, enc_b, batch, gf, rW1, rb1,
                                                 rW2, rb2, sparse, hb, ei, epos, lpre,
                                                 boff, deg, csrc, rowptr);

  const int GX = (NN + 127) / 128;  // 391 gemm blocks per expert

  // shared layer-0 aggregation of h (identical input for every expert)
  k_spmm256<<<(NN + 3) / 4, 256, 0, stream>>>(rowptr, csrc, hb, agg0);
  for (int e0 = 0; e0 < 8; e0 += grp) {
    // layer 0 (batched over grp experts): plain-layout inputs -> interleaved Y
    k_gemm<<<dim3(GX, grp), 512, 0, stream>>>(
        hb, 0, 256, agg0, 0, 256, WrT + e0 * 65536, WnT + e0 * 65536, 65536,
        hid_b + e0 * 256, 256, heb, 256, RS, 1, nullptr, nullptr, 0, nullptr, nullptr, 0);
    // layer 1 (interleaved throughout)
    k_spmm_intl<<<NN, RS / 4, 0, stream>>>(rowptr, csrc, heb, aggb, RS);
    k_gemm<<<dim3(GX, grp), 512, 0, stream>>>(
        heb, 256, RS, aggb, 256, RS, WrT + (8 + e0) * 65536, WnT + (8 + e0) * 65536, 65536,
        hid_b + (8 + e0) * 256, 256, heb, 256, RS, 1, nullptr, nullptr, 0, nullptr, nullptr, 0);
    // layer 2 + fused out-projection (he2 never materialized)
    k_spmm_intl<<<NN, RS / 4, 0, stream>>>(rowptr, csrc, heb, aggb, RS);
    k_gemm<<<dim3(GX, grp), 512, 0, stream>>>(
        heb, 256, RS, aggb, 256, RS, WrT + (16 + e0) * 65536, WnT + (16 + e0) * 65536, 65536,
        hid_b + (16 + e0) * 256, 256, nullptr, 0, 256, 1, out_Wr, out_Wn, e0,
        Y4self, Y4nb, 1);
  }
  k_combine<<<(NN * 8 + 255) / 256, 256, 0, stream>>>(rowptr, csrc, Y4self, Y4nb, sparse,
                                                      out_b, out);
}